// Round 6
// baseline (396.111 us; speedup 1.0000x reference)
//
#include <hip/hip_runtime.h>

#define NF 768
#define D1 10
#define D2 128
#define BM 64

typedef __attribute__((ext_vector_type(8))) short bf16x8;
typedef __attribute__((ext_vector_type(16))) float f32x16;

static __device__ __forceinline__ float sigf(float v){ return 1.0f/(1.0f+__expf(-v)); }
static __device__ __forceinline__ float tanhfast(float v){ return 2.0f/(1.0f+__expf(-2.0f*v)) - 1.0f; }
static __device__ __forceinline__ short f2bf(float f){
    unsigned u = __float_as_uint(f);
    u += 0x7fffu + ((u>>16)&1u);
    return (short)(u>>16);
}

// ---- degree counts ----
__global__ void k_deg(const int* __restrict__ dst, int* __restrict__ cnt, int E){
    int e = blockIdx.x*256 + threadIdx.x;
    if(e<E) atomicAdd(&cnt[dst[e]], 1);
}

// ---- scan (rowptr/rowcur) + dinv fused, single block ----
__global__ __launch_bounds__(256) void k_scan(const int* __restrict__ cnt,
                                              int* __restrict__ rowptr, int* __restrict__ rowcur,
                                              float* __restrict__ dinv, int N, int E){
    __shared__ int part[256];
    int t = threadIdx.x;
    int C = (N+255)/256;
    int lo = t*C, hi = lo+C; if(hi>N) hi=N; if(lo>N) lo=N;
    int s=0;
    for(int i=lo;i<hi;i++) s += cnt[i];
    part[t]=s;
    __syncthreads();
    if(t==0){
        int run=0;
        for(int i=0;i<256;i++){ int v=part[i]; part[i]=run; run+=v; }
        rowptr[N]=E;
    }
    __syncthreads();
    int run = part[t];
    for(int i=lo;i<hi;i++){
        rowptr[i]=run; rowcur[i]=run; run += cnt[i];
        dinv[i] = rsqrtf((float)cnt[i] + 1.0f);
    }
}

__global__ void k_fill(const int* __restrict__ src, const int* __restrict__ dst,
                       const float* __restrict__ dinv, int* __restrict__ rowcur,
                       int* __restrict__ esrc, float* __restrict__ enorm, int E){
    int e = blockIdx.x*256 + threadIdx.x;
    if(e>=E) return;
    int s=src[e], d=dst[e];
    int pos = atomicAdd(&rowcur[d], 1);
    esrc[pos]=s;
    enorm[pos]=dinv[s]*dinv[d];
}

// ---- h1 = x @ W1 ----
__global__ __launch_bounds__(256) void k_h1(const float* __restrict__ x,
                                            const float* __restrict__ W1,
                                            float* __restrict__ h1, int N){
    __shared__ float wt[D1*NF];
    for(int idx=threadIdx.x; idx<NF*D1; idx+=256){
        int k=idx/D1, c=idx-k*D1;
        wt[c*NF+k]=W1[idx];
    }
    __syncthreads();
    int row = blockIdx.x*4 + (threadIdx.x>>6);
    int lane = threadIdx.x&63;
    if(row>=N) return;
    const float4* xr = (const float4*)(x + (size_t)row*NF);
    float acc[D1];
#pragma unroll
    for(int c=0;c<D1;c++) acc[c]=0.f;
#pragma unroll
    for(int i=0;i<3;i++){
        float4 v = xr[lane + 64*i];
#pragma unroll
        for(int c=0;c<D1;c++){
            float4 w = *(const float4*)&wt[c*NF + (lane+64*i)*4];
            acc[c] += v.x*w.x + v.y*w.y + v.z*w.z + v.w*w.w;
        }
    }
#pragma unroll
    for(int c=0;c<D1;c++){
        float v=acc[c];
#pragma unroll
        for(int off=32;off;off>>=1) v += __shfl_down(v,off,64);
        acc[c]=v;
    }
    if(lane==0){
#pragma unroll
        for(int c=0;c<D1;c++) h1[(size_t)row*D1+c]=acc[c];
    }
}

// ---- layer-1 CSR gather + relu ----
__global__ __launch_bounds__(256) void k_gath1(const float* __restrict__ h1,
        const int* __restrict__ rowptr, const int* __restrict__ esrc,
        const float* __restrict__ enorm, const float* __restrict__ dinv,
        const float* __restrict__ b1, float* __restrict__ h, int N){
    int node = blockIdx.x*4 + (threadIdx.x>>6);
    int lane = threadIdx.x&63;
    if(node>=N) return;
    int e0=rowptr[node], e1=rowptr[node+1];
    float acc[D1];
#pragma unroll
    for(int c=0;c<D1;c++) acc[c]=0.f;
    for(int e=e0+lane; e<e1; e+=64){
        int s=esrc[e]; float w=enorm[e];
        const float* hr = h1 + (size_t)s*D1;
#pragma unroll
        for(int c=0;c<D1;c++) acc[c] += hr[c]*w;
    }
    if(lane==0){
        float di=dinv[node], d2=di*di;
        const float* hr = h1 + (size_t)node*D1;
#pragma unroll
        for(int c=0;c<D1;c++) acc[c] += hr[c]*d2;
    }
#pragma unroll
    for(int c=0;c<D1;c++){
        float v=acc[c];
#pragma unroll
        for(int off=32;off;off>>=1) v += __shfl_down(v,off,64);
        acc[c]=v;
    }
    if(lane==0){
#pragma unroll
        for(int c=0;c<D1;c++){
            float v = acc[c] + b1[c];
            h[(size_t)node*D1+c] = v>0.f ? v : 0.f;
        }
    }
}

__global__ __launch_bounds__(128) void k_hz(const float* __restrict__ h,
                                            const float* __restrict__ W2,
                                            float* __restrict__ hz, int N){
    __shared__ float w2s[D1*D2];
    int j = threadIdx.x;
    for(int i=j;i<D1*D2;i+=128) w2s[i]=W2[i];
    __syncthreads();
    int n = blockIdx.x;
    if(n>=N) return;
    const float* hr = h + (size_t)n*D1;
    float acc=0.f;
#pragma unroll
    for(int k=0;k<D1;k++) acc += hr[k]*w2s[k*D2+j];
    hz[(size_t)n*D2+j]=acc;
}

// ---- layer-2 CSR gather (fused zfin), writes bf16 zb table ----
__global__ __launch_bounds__(128) void k_gath2(const float* __restrict__ hz,
        const int* __restrict__ rowptr, const int* __restrict__ esrc,
        const float* __restrict__ enorm, const float* __restrict__ dinv,
        const float* __restrict__ b2, ushort* __restrict__ zb, int N){
    int n = blockIdx.x;
    int c = threadIdx.x;
    int e0 = rowptr[n], e1 = rowptr[n+1];
    float di = dinv[n];
    float acc = hz[(size_t)n*D2+c]*di*di + b2[c];
    int e = e0;
    for(; e+1<e1; e+=2){
        int s0=esrc[e], s1=esrc[e+1];
        float w0=enorm[e], w1=enorm[e+1];
        acc += hz[(size_t)s0*D2+c]*w0 + hz[(size_t)s1*D2+c]*w1;
    }
    if(e<e1) acc += hz[(size_t)esrc[e]*D2+c]*enorm[e];
    zb[(size_t)n*D2+c] = (ushort)f2bf(acc);
}

// ---- B fragment image over FULL K=1024: 12 frags x 64 ks16 x 64 lanes x 8 bf16 ----
__global__ void k_wimgB(const float* __restrict__ Wih, ushort* __restrict__ img){
    int gid = blockIdx.x*256 + threadIdx.x;        // 12*64*64 = 49152
    if(gid >= 12*64*64) return;
    int l = gid & 63;
    int ks16 = (gid>>6) & 63;
    int f = gid >> 12;
    int dd = l & 31, kb = l>>5;
    int wn = f/3, gi = f - wn*3;
    int gbase = (gi==0)?0:((gi==1)?256:384);
    int wrow = gbase + wn*32 + dd;
    int k = ks16*16 + kb*8;
    const float* p = Wih + (size_t)wrow*1024 + k;
    float4 v0=*(const float4*)p, v1=*(const float4*)(p+4);
    bf16x8 o;
    o[0]=f2bf(v0.x); o[1]=f2bf(v0.y); o[2]=f2bf(v0.z); o[3]=f2bf(v0.w);
    o[4]=f2bf(v1.x); o[5]=f2bf(v1.y); o[6]=f2bf(v1.z); o[7]=f2bf(v1.w);
    *(bf16x8*)(img + (size_t)gid*8) = o;
}

// ---- split staging (T14): issue 4 groups -> (compute) -> write 4 groups ----
// feat k-layout: groups G 0..15 = z_h, 16..111 = r_emb, 112..127 = z_t (8 k each)
// LDS fragment-linear: slot16B = (mb*16 + s)*64 + r31 + 32*kh, s=ks16-local, kh=k-half
struct PendG { float4 lo, hi; };

static __device__ __forceinline__ void issue_groups(PendG* __restrict__ pend, int ch1, int jbase,
        int tid, int t0, int T, const float* __restrict__ remb,
        const ushort* __restrict__ zb, const int* __restrict__ trip){
    int row = tid>>2, q = tid&3;
    int tc = t0+row; if(tc>=T) tc=T-1;
#pragma unroll
    for(int j=0;j<4;j++){
        int gl = q + 4*(jbase+j);
        int G = ch1*32 + gl;
        if(G < 16){
            pend[j].lo = *(const float4*)(zb + (size_t)trip[3*tc]*D2 + G*8);
        } else if(G < 112){
            const float* p = remb + (size_t)tc*NF + (size_t)(G-16)*8;
            pend[j].lo = *(const float4*)p;
            pend[j].hi = *(const float4*)(p+4);
        } else {
            pend[j].lo = *(const float4*)(zb + (size_t)trip[3*tc+2]*D2 + (size_t)(G-112)*8);
        }
    }
}

static __device__ __forceinline__ void write_groups(ushort* __restrict__ buf,
        const PendG* __restrict__ pend, int ch1, int jbase, int tid){
    int row = tid>>2, q = tid&3;
    int mb = row>>5, r31 = row&31;
#pragma unroll
    for(int j=0;j<4;j++){
        int gl = q + 4*(jbase+j);
        int G = ch1*32 + gl;
        int slot = ((mb*16 + (gl>>1))*64 + r31 + 32*(gl&1))*8;
        if(G >= 16 && G < 112){
            bf16x8 o;
            o[0]=f2bf(pend[j].lo.x); o[1]=f2bf(pend[j].lo.y); o[2]=f2bf(pend[j].lo.z); o[3]=f2bf(pend[j].lo.w);
            o[4]=f2bf(pend[j].hi.x); o[5]=f2bf(pend[j].hi.y); o[6]=f2bf(pend[j].hi.z); o[7]=f2bf(pend[j].hi.w);
            *(bf16x8*)(buf + slot) = o;
        } else {
            *(float4*)(buf + slot) = pend[j].lo;
        }
    }
}

// ---- fused MFMA GEMM + LSTM. 4 chunks x 16 ks16, frag-linear dbuf LDS, split-stage ----
__global__ __launch_bounds__(256,2) void k_big(
    const float* __restrict__ remb, const ushort* __restrict__ img,
    const ushort* __restrict__ zb, const float* __restrict__ b_ih,
    const float* __restrict__ b_hh, const int* __restrict__ trip,
    float* __restrict__ score, int T)
{
    __shared__ ushort Abuf[2][32*64*8];   // 2 x 32 KB, fragment-linear
    int tid=threadIdx.x, lane=tid&63, wn=tid>>6;
    int l31=lane&31, lh=lane>>5;
    int t0=blockIdx.x*BM;

    const ushort* wb0 = img + ((size_t)(wn*3+0)*64*64 + lane)*8;
    const ushort* wb1 = img + ((size_t)(wn*3+1)*64*64 + lane)*8;
    const ushort* wb2 = img + ((size_t)(wn*3+2)*64*64 + lane)*8;
    const int abase = lane*8;

    f32x16 acc[2][3];
    const f32x16 zer = {0,0,0,0,0,0,0,0,0,0,0,0,0,0,0,0};
#pragma unroll
    for(int m=0;m<2;m++)
#pragma unroll
        for(int g=0;g<3;g++) acc[m][g]=zer;

    // B ring prefetch: global steps 0..3
    bf16x8 qb[4][3];
#pragma unroll
    for(int p=0;p<4;p++){
        qb[p][0]=*(const bf16x8*)(wb0+(size_t)p*512);
        qb[p][1]=*(const bf16x8*)(wb1+(size_t)p*512);
        qb[p][2]=*(const bf16x8*)(wb2+(size_t)p*512);
    }

    PendG pend[4];
    // prologue: stage chunk 0
    issue_groups(pend, 0, 0, tid, t0, T, remb, zb, trip);
    write_groups(Abuf[0], pend, 0, 0, tid);
    issue_groups(pend, 0, 4, tid, t0, T, remb, zb, trip);
    write_groups(Abuf[0], pend, 0, 4, tid);
    __syncthreads();

#define STEP(C_) { \
        const int bs_=(C_)&3, as_=(C_)&1; \
        bf16x8 a0=pa[as_][0], a1=pa[as_][1]; \
        bf16x8 b0=qb[bs_][0], b1=qb[bs_][1], b2v=qb[bs_][2]; \
        if((C_)+2<16){ \
            pa[as_][0]=*(const bf16x8*)&cur[((C_)+2)*512 + abase]; \
            pa[as_][1]=*(const bf16x8*)&cur[(16+(C_)+2)*512 + abase]; \
        } \
        if(ch*16+(C_)+4 < 64){ \
            size_t ko_=(size_t)(ch*16+(C_)+4)*512; \
            qb[bs_][0]=*(const bf16x8*)(wb0+ko_); \
            qb[bs_][1]=*(const bf16x8*)(wb1+ko_); \
            qb[bs_][2]=*(const bf16x8*)(wb2+ko_); \
        } \
        acc[0][0]=__builtin_amdgcn_mfma_f32_32x32x16_bf16(a0,b0 ,acc[0][0],0,0,0); \
        acc[0][1]=__builtin_amdgcn_mfma_f32_32x32x16_bf16(a0,b1 ,acc[0][1],0,0,0); \
        acc[0][2]=__builtin_amdgcn_mfma_f32_32x32x16_bf16(a0,b2v,acc[0][2],0,0,0); \
        acc[1][0]=__builtin_amdgcn_mfma_f32_32x32x16_bf16(a1,b0 ,acc[1][0],0,0,0); \
        acc[1][1]=__builtin_amdgcn_mfma_f32_32x32x16_bf16(a1,b1 ,acc[1][1],0,0,0); \
        acc[1][2]=__builtin_amdgcn_mfma_f32_32x32x16_bf16(a1,b2v,acc[1][2],0,0,0); \
    }

    for(int ch=0; ch<4; ++ch){
        ushort* cur = Abuf[ch&1];
        ushort* nxt = Abuf[(ch+1)&1];
        const bool more = (ch<3);
        if(more) issue_groups(pend, ch+1, 0, tid, t0, T, remb, zb, trip);
        bf16x8 pa[2][2];
        pa[0][0]=*(const bf16x8*)&cur[0*512 + abase];
        pa[0][1]=*(const bf16x8*)&cur[16*512 + abase];
        pa[1][0]=*(const bf16x8*)&cur[1*512 + abase];
        pa[1][1]=*(const bf16x8*)&cur[17*512 + abase];
        __builtin_amdgcn_s_setprio(1);
#pragma unroll
        for(int c=0;c<8;c++) STEP(c)
        __builtin_amdgcn_s_setprio(0);
        if(more){
            write_groups(nxt, pend, ch+1, 0, tid);
            issue_groups(pend, ch+1, 4, tid, t0, T, remb, zb, trip);
        }
        __builtin_amdgcn_s_setprio(1);
#pragma unroll
        for(int c=8;c<16;c++) STEP(c)
        __builtin_amdgcn_s_setprio(0);
        if(more) write_groups(nxt, pend, ch+1, 4, tid);
        __syncthreads();
    }
#undef STEP

    // ---- epilogue: bias + LSTM + row-sum reduce (reuse Abuf as rowsum) ----
    float* rowsum = (float*)&Abuf[0][0];
    if(tid<BM) rowsum[tid]=0.f;
    __syncthreads();
    int d = wn*32+l31;
    float bi=b_ih[d]+b_hh[d];
    float bg=b_ih[256+d]+b_hh[256+d];
    float bo=b_ih[384+d]+b_hh[384+d];
#pragma unroll
    for(int m=0;m<2;m++){
#pragma unroll
        for(int r=0;r<16;r++){
            int row = m*32 + (r&3)+8*(r>>2)+4*lh;
            float ig = acc[m][0][r] + bi;
            float gg = acc[m][1][r] + bg;
            float og = acc[m][2][r] + bo;
            float cc = sigf(ig)*tanhfast(gg);
            float ov = sigf(og)*tanhfast(cc);
#pragma unroll
            for(int off=1; off<32; off<<=1) ov += __shfl_xor(ov, off, 64);
            if(l31==0) atomicAdd(&rowsum[row], ov);
        }
    }
    __syncthreads();
    if(tid < BM){
        int t = t0 + tid;
        if(t < T) score[t] = sigf(rowsum[tid]);
    }
}

extern "C" void kernel_launch(void* const* d_in, const int* in_sizes, int n_in,
                              void* d_out, int out_size, void* d_ws, size_t ws_size,
                              hipStream_t stream){
    const float* x    = (const float*)d_in[0];
    const float* remb = (const float*)d_in[1];
    const float* W1   = (const float*)d_in[2];
    const float* b1   = (const float*)d_in[3];
    const float* W2   = (const float*)d_in[4];
    const float* b2   = (const float*)d_in[5];
    const float* Wih  = (const float*)d_in[6];
    const float* b_ih = (const float*)d_in[8];
    const float* b_hh = (const float*)d_in[9];
    const int*   ei   = (const int*)d_in[10];
    const int*   trip = (const int*)d_in[11];
    float* score = (float*)d_out;

    const int N = in_sizes[0]/NF;       // 15000
    const int E = in_sizes[10]/2;       // 200000
    const int T = in_sizes[11]/3;       // 100000
    const int* src = ei;
    const int* dst = ei + E;

    float* ws = (float*)d_ws;
    size_t o = 0;
    ushort* img  = (ushort*)(ws+o); o += (size_t)12*64*64*8/2;   // 786 KB
    ushort* zb   = (ushort*)(ws+o); o += (size_t)N*D2/2;         // 3.84 MB
    int*   cnt    = (int*)(ws+o);   o += (size_t)((N+8)&~7);
    int*   rowptr = (int*)(ws+o);   o += (size_t)((N+8)&~7);
    int*   rowcur = (int*)(ws+o);   o += (size_t)((N+8)&~7);
    int*   esrc   = (int*)(ws+o);   o += (size_t)E;
    float* enorm  = ws+o;           o += (size_t)E;
    float* dinv   = ws+o;           o += (size_t)((N+7)&~7);
    float* h1     = ws+o;           o += (size_t)N*D1;
    float* hbuf   = ws+o;           o += (size_t)N*D1;
    float* hz     = ws+o;           o += (size_t)N*D2;
    (void)ws_size; (void)n_in; (void)out_size;

    hipMemsetAsync(cnt, 0, (size_t)N*sizeof(int), stream);

    k_wimgB<<<dim3((12*64*64+255)/256), dim3(256), 0, stream>>>(Wih, img);
    k_deg  <<<dim3((E+255)/256), dim3(256), 0, stream>>>(dst, cnt, E);
    k_scan <<<dim3(1), dim3(256), 0, stream>>>(cnt, rowptr, rowcur, dinv, N, E);
    k_fill <<<dim3((E+255)/256), dim3(256), 0, stream>>>(src, dst, dinv, rowcur, esrc, enorm, E);
    k_h1   <<<dim3((N+3)/4), dim3(256), 0, stream>>>(x, W1, h1, N);
    k_gath1<<<dim3((N+3)/4), dim3(256), 0, stream>>>(h1, rowptr, esrc, enorm, dinv, b1, hbuf, N);
    k_hz   <<<dim3(N), dim3(128), 0, stream>>>(hbuf, W2, hz, N);
    k_gath2<<<dim3(N), dim3(128), 0, stream>>>(hz, rowptr, esrc, enorm, dinv, b2, zb, N);
    k_big  <<<dim3((T+BM-1)/BM), dim3(256), 0, stream>>>(remb, img, zb, b_ih, b_hh, trip, score, T);
}

// Round 7
// 316.295 us; speedup vs baseline: 1.2523x; 1.2523x over previous
//
#include <hip/hip_runtime.h>

#define NF 768
#define D1 10
#define D2 128
#define BM 64

typedef __attribute__((ext_vector_type(8))) short bf16x8;
typedef __attribute__((ext_vector_type(16))) float f32x16;

static __device__ __forceinline__ float sigf(float v){ return 1.0f/(1.0f+__expf(-v)); }
static __device__ __forceinline__ float tanhfast(float v){ return 2.0f/(1.0f+__expf(-2.0f*v)) - 1.0f; }
static __device__ __forceinline__ short f2bf(float f){
    unsigned u = __float_as_uint(f);
    u += 0x7fffu + ((u>>16)&1u);
    return (short)(u>>16);
}

// async global->LDS, 16B per lane, LDS dest = wave-uniform base + lane*16
static __device__ __forceinline__ void gload16(const void* g, void* l){
    __builtin_amdgcn_global_load_lds(
        (const __attribute__((address_space(1))) unsigned int*)(unsigned long long)g,
        (__attribute__((address_space(3))) unsigned int*)(unsigned long long)l,
        16, 0, 0);
}

static __device__ __forceinline__ bf16x8 cvt8(float4 a, float4 b){
    unsigned u0,u1,u2,u3;
    asm("v_cvt_pk_bf16_f32 %0, %1, %2" : "=v"(u0) : "v"(a.x), "v"(a.y));
    asm("v_cvt_pk_bf16_f32 %0, %1, %2" : "=v"(u1) : "v"(a.z), "v"(a.w));
    asm("v_cvt_pk_bf16_f32 %0, %1, %2" : "=v"(u2) : "v"(b.x), "v"(b.y));
    asm("v_cvt_pk_bf16_f32 %0, %1, %2" : "=v"(u3) : "v"(b.z), "v"(b.w));
    union { unsigned u[4]; bf16x8 v; } r;
    r.u[0]=u0; r.u[1]=u1; r.u[2]=u2; r.u[3]=u3;
    return r.v;
}

// ---- degree counts ----
__global__ void k_deg(const int* __restrict__ dst, int* __restrict__ cnt, int E){
    int e = blockIdx.x*256 + threadIdx.x;
    if(e<E) atomicAdd(&cnt[dst[e]], 1);
}

// ---- scan (rowptr/rowcur) + dinv fused, single block ----
__global__ __launch_bounds__(256) void k_scan(const int* __restrict__ cnt,
                                              int* __restrict__ rowptr, int* __restrict__ rowcur,
                                              float* __restrict__ dinv, int N, int E){
    __shared__ int part[256];
    int t = threadIdx.x;
    int C = (N+255)/256;
    int lo = t*C, hi = lo+C; if(hi>N) hi=N; if(lo>N) lo=N;
    int s=0;
    for(int i=lo;i<hi;i++) s += cnt[i];
    part[t]=s;
    __syncthreads();
    if(t==0){
        int run=0;
        for(int i=0;i<256;i++){ int v=part[i]; part[i]=run; run+=v; }
        rowptr[N]=E;
    }
    __syncthreads();
    int run = part[t];
    for(int i=lo;i<hi;i++){
        rowptr[i]=run; rowcur[i]=run; run += cnt[i];
        dinv[i] = rsqrtf((float)cnt[i] + 1.0f);
    }
}

__global__ void k_fill(const int* __restrict__ src, const int* __restrict__ dst,
                       const float* __restrict__ dinv, int* __restrict__ rowcur,
                       int* __restrict__ esrc, float* __restrict__ enorm, int E){
    int e = blockIdx.x*256 + threadIdx.x;
    if(e>=E) return;
    int s=src[e], d=dst[e];
    int pos = atomicAdd(&rowcur[d], 1);
    esrc[pos]=s;
    enorm[pos]=dinv[s]*dinv[d];
}

// ---- h1 = x @ W1 ----
__global__ __launch_bounds__(256) void k_h1(const float* __restrict__ x,
                                            const float* __restrict__ W1,
                                            float* __restrict__ h1, int N){
    __shared__ float wt[D1*NF];
    for(int idx=threadIdx.x; idx<NF*D1; idx+=256){
        int k=idx/D1, c=idx-k*D1;
        wt[c*NF+k]=W1[idx];
    }
    __syncthreads();
    int row = blockIdx.x*4 + (threadIdx.x>>6);
    int lane = threadIdx.x&63;
    if(row>=N) return;
    const float4* xr = (const float4*)(x + (size_t)row*NF);
    float acc[D1];
#pragma unroll
    for(int c=0;c<D1;c++) acc[c]=0.f;
#pragma unroll
    for(int i=0;i<3;i++){
        float4 v = xr[lane + 64*i];
#pragma unroll
        for(int c=0;c<D1;c++){
            float4 w = *(const float4*)&wt[c*NF + (lane+64*i)*4];
            acc[c] += v.x*w.x + v.y*w.y + v.z*w.z + v.w*w.w;
        }
    }
#pragma unroll
    for(int c=0;c<D1;c++){
        float v=acc[c];
#pragma unroll
        for(int off=32;off;off>>=1) v += __shfl_down(v,off,64);
        acc[c]=v;
    }
    if(lane==0){
#pragma unroll
        for(int c=0;c<D1;c++) h1[(size_t)row*D1+c]=acc[c];
    }
}

// ---- layer-1 CSR gather + relu ----
__global__ __launch_bounds__(256) void k_gath1(const float* __restrict__ h1,
        const int* __restrict__ rowptr, const int* __restrict__ esrc,
        const float* __restrict__ enorm, const float* __restrict__ dinv,
        const float* __restrict__ b1, float* __restrict__ h, int N){
    int node = blockIdx.x*4 + (threadIdx.x>>6);
    int lane = threadIdx.x&63;
    if(node>=N) return;
    int e0=rowptr[node], e1=rowptr[node+1];
    float acc[D1];
#pragma unroll
    for(int c=0;c<D1;c++) acc[c]=0.f;
    for(int e=e0+lane; e<e1; e+=64){
        int s=esrc[e]; float w=enorm[e];
        const float* hr = h1 + (size_t)s*D1;
#pragma unroll
        for(int c=0;c<D1;c++) acc[c] += hr[c]*w;
    }
    if(lane==0){
        float di=dinv[node], d2=di*di;
        const float* hr = h1 + (size_t)node*D1;
#pragma unroll
        for(int c=0;c<D1;c++) acc[c] += hr[c]*d2;
    }
#pragma unroll
    for(int c=0;c<D1;c++){
        float v=acc[c];
#pragma unroll
        for(int off=32;off;off>>=1) v += __shfl_down(v,off,64);
        acc[c]=v;
    }
    if(lane==0){
#pragma unroll
        for(int c=0;c<D1;c++){
            float v = acc[c] + b1[c];
            h[(size_t)node*D1+c] = v>0.f ? v : 0.f;
        }
    }
}

__global__ __launch_bounds__(128) void k_hz(const float* __restrict__ h,
                                            const float* __restrict__ W2,
                                            float* __restrict__ hz, int N){
    __shared__ float w2s[D1*D2];
    int j = threadIdx.x;
    for(int i=j;i<D1*D2;i+=128) w2s[i]=W2[i];
    __syncthreads();
    int n = blockIdx.x;
    if(n>=N) return;
    const float* hr = h + (size_t)n*D1;
    float acc=0.f;
#pragma unroll
    for(int k=0;k<D1;k++) acc += hr[k]*w2s[k*D2+j];
    hz[(size_t)n*D2+j]=acc;
}

// ---- layer-2 CSR gather (fused zfin), writes fp32 z table ----
__global__ __launch_bounds__(128) void k_gath2(const float* __restrict__ hz,
        const int* __restrict__ rowptr, const int* __restrict__ esrc,
        const float* __restrict__ enorm, const float* __restrict__ dinv,
        const float* __restrict__ b2, float* __restrict__ zbf, int N){
    int n = blockIdx.x;
    int c = threadIdx.x;
    int e0 = rowptr[n], e1 = rowptr[n+1];
    float di = dinv[n];
    float acc = hz[(size_t)n*D2+c]*di*di + b2[c];
    int e = e0;
    for(; e+1<e1; e+=2){
        int s0=esrc[e], s1=esrc[e+1];
        float w0=enorm[e], w1=enorm[e+1];
        acc += hz[(size_t)s0*D2+c]*w0 + hz[(size_t)s1*D2+c]*w1;
    }
    if(e<e1) acc += hz[(size_t)esrc[e]*D2+c]*enorm[e];
    zbf[(size_t)n*D2+c] = acc;
}

// ---- B fragment image over FULL K=1024: 12 frags x 64 ks16 x 64 lanes x 8 bf16 ----
__global__ void k_wimgB(const float* __restrict__ Wih, ushort* __restrict__ img){
    int gid = blockIdx.x*256 + threadIdx.x;        // 12*64*64 = 49152
    if(gid >= 12*64*64) return;
    int l = gid & 63;
    int ks16 = (gid>>6) & 63;
    int f = gid >> 12;
    int dd = l & 31, kb = l>>5;
    int wn = f/3, gi = f - wn*3;
    int gbase = (gi==0)?0:((gi==1)?256:384);
    int wrow = gbase + wn*32 + dd;
    int k = ks16*16 + kb*8;
    const float* p = Wih + (size_t)wrow*1024 + k;
    float4 v0=*(const float4*)p, v1=*(const float4*)(p+4);
    bf16x8 o;
    o[0]=f2bf(v0.x); o[1]=f2bf(v0.y); o[2]=f2bf(v0.z); o[3]=f2bf(v0.w);
    o[4]=f2bf(v1.x); o[5]=f2bf(v1.y); o[6]=f2bf(v1.z); o[7]=f2bf(v1.w);
    *(bf16x8*)(img + (size_t)gid*8) = o;
}

// ---- fused MFMA GEMM + LSTM. K=1024 feat = [z_h|r_emb|z_t], fp32 A via
// global_load_lds into 4-deep LDS ring, counted vmcnt + raw barriers ----
__global__ __launch_bounds__(256,2) void k_big(
    const float* __restrict__ remb, const ushort* __restrict__ img,
    const float* __restrict__ zbf, const float* __restrict__ b_ih,
    const float* __restrict__ b_hh, const int* __restrict__ trip,
    float* __restrict__ score, int T)
{
    __shared__ float ring[4][64*64];   // 4 x 16 KB
    int tid=threadIdx.x, lane=tid&63, w=tid>>6;
    int l31=lane&31, lh=lane>>5;
    int t0=blockIdx.x*BM;

    // staging geometry: wave w stages rows [w*16, w*16+16), 4 issues of 4 rows
    const int l16 = lane>>4;           // row within 4-row group
    size_t rbo[4]; const float* zh4[4]; const float* zt4[4]; int lsl[4];
#pragma unroll
    for(int j=0;j<4;j++){
        int row = w*16 + j*4 + l16;
        int tc = t0 + row; if(tc>=T) tc=T-1;
        rbo[j] = (size_t)tc*NF;
        int th = trip[3*tc], tt = trip[3*tc+2];
        zh4[j] = zbf + (size_t)th*D2;
        zt4[j] = zbf + (size_t)tt*D2;
        lsl[j] = ((lane&15) ^ (row&15))*4;   // pre-swizzled source slot (floats)
    }

    const ushort* wb0 = img + ((size_t)(w*3+0)*64*64 + lane)*8;
    const ushort* wb1 = img + ((size_t)(w*3+1)*64*64 + lane)*8;
    const ushort* wb2 = img + ((size_t)(w*3+2)*64*64 + lane)*8;
    const int base0 = l31*64;
    const int base1 = (32+l31)*64;
    const int rx = lane&15;

    f32x16 acc[2][3];
    const f32x16 zer = {0,0,0,0,0,0,0,0,0,0,0,0,0,0,0,0};
#pragma unroll
    for(int m=0;m<2;m++)
#pragma unroll
        for(int g=0;g<3;g++) acc[m][g]=zer;

#define ISSUE(C_) { \
    float* dst_ = &ring[(C_)&3][(w*16)*64]; \
    _Pragma("unroll") \
    for(int j_=0;j_<4;j_++){ \
        const float* src_; \
        if((C_)<2)       src_ = zh4[j_] + (C_)*64 + lsl[j_]; \
        else if((C_)<14) src_ = remb + rbo[j_] + ((C_)-2)*64 + lsl[j_]; \
        else             src_ = zt4[j_] + ((C_)-14)*64 + lsl[j_]; \
        gload16(src_, dst_ + j_*4*64); \
    } }

    // prologue: 3 chunks in flight + B ring (gs 0,1)
    ISSUE(0) ISSUE(1) ISSUE(2)
    bf16x8 qb[2][3];
    qb[0][0]=*(const bf16x8*)(wb0);     qb[0][1]=*(const bf16x8*)(wb1);     qb[0][2]=*(const bf16x8*)(wb2);
    qb[1][0]=*(const bf16x8*)(wb0+512); qb[1][1]=*(const bf16x8*)(wb1+512); qb[1][2]=*(const bf16x8*)(wb2+512);

#define KSTEP(C_,S_) { \
    const float4 a00_ = *(const float4*)&cur_[base0 + ((((S_)*4+lh*2)  )^rx)*4]; \
    const float4 a01_ = *(const float4*)&cur_[base0 + ((((S_)*4+lh*2)+1)^rx)*4]; \
    const float4 a10_ = *(const float4*)&cur_[base1 + ((((S_)*4+lh*2)  )^rx)*4]; \
    const float4 a11_ = *(const float4*)&cur_[base1 + ((((S_)*4+lh*2)+1)^rx)*4]; \
    bf16x8 A0_ = cvt8(a00_, a01_); \
    bf16x8 A1_ = cvt8(a10_, a11_); \
    bf16x8 B0_=qb[(S_)&1][0], B1_=qb[(S_)&1][1], B2_=qb[(S_)&1][2]; \
    if((C_)*4+(S_)+2 < 64){ \
        size_t ko_ = (size_t)((C_)*4+(S_)+2)*512; \
        qb[(S_)&1][0]=*(const bf16x8*)(wb0+ko_); \
        qb[(S_)&1][1]=*(const bf16x8*)(wb1+ko_); \
        qb[(S_)&1][2]=*(const bf16x8*)(wb2+ko_); \
    } \
    acc[0][0]=__builtin_amdgcn_mfma_f32_32x32x16_bf16(A0_,B0_,acc[0][0],0,0,0); \
    acc[0][1]=__builtin_amdgcn_mfma_f32_32x32x16_bf16(A0_,B1_,acc[0][1],0,0,0); \
    acc[0][2]=__builtin_amdgcn_mfma_f32_32x32x16_bf16(A0_,B2_,acc[0][2],0,0,0); \
    acc[1][0]=__builtin_amdgcn_mfma_f32_32x32x16_bf16(A1_,B0_,acc[1][0],0,0,0); \
    acc[1][1]=__builtin_amdgcn_mfma_f32_32x32x16_bf16(A1_,B1_,acc[1][1],0,0,0); \
    acc[1][2]=__builtin_amdgcn_mfma_f32_32x32x16_bf16(A1_,B2_,acc[1][2],0,0,0); \
}

#define CHUNK(C_) { \
    asm volatile("s_waitcnt vmcnt(12)" ::: "memory"); \
    __builtin_amdgcn_s_barrier(); \
    __builtin_amdgcn_sched_barrier(0); \
    if((C_)+3 < 16) { ISSUE((C_)+3) } \
    const float* cur_ = &ring[(C_)&3][0]; \
    __builtin_amdgcn_s_setprio(1); \
    KSTEP(C_,0) KSTEP(C_,1) KSTEP(C_,2) KSTEP(C_,3) \
    __builtin_amdgcn_s_setprio(0); \
}

    CHUNK(0)  CHUNK(1)  CHUNK(2)  CHUNK(3)
    CHUNK(4)  CHUNK(5)  CHUNK(6)  CHUNK(7)
    CHUNK(8)  CHUNK(9)  CHUNK(10) CHUNK(11)
    CHUNK(12) CHUNK(13) CHUNK(14) CHUNK(15)
#undef CHUNK
#undef KSTEP
#undef ISSUE

    // ---- epilogue: bias + LSTM + row-sum reduce (reuse ring[0] as rowsum) ----
    float* rowsum = &ring[0][0];
    __syncthreads();
    if(tid<BM) rowsum[tid]=0.f;
    __syncthreads();
    int d = w*32+l31;
    float bi=b_ih[d]+b_hh[d];
    float bg=b_ih[256+d]+b_hh[256+d];
    float bo=b_ih[384+d]+b_hh[384+d];
#pragma unroll
    for(int m=0;m<2;m++){
#pragma unroll
        for(int r=0;r<16;r++){
            int row = m*32 + (r&3)+8*(r>>2)+4*lh;
            float ig = acc[m][0][r] + bi;
            float gg = acc[m][1][r] + bg;
            float og = acc[m][2][r] + bo;
            float cc = sigf(ig)*tanhfast(gg);
            float ov = sigf(og)*tanhfast(cc);
#pragma unroll
            for(int off=1; off<32; off<<=1) ov += __shfl_xor(ov, off, 64);
            if(l31==0) atomicAdd(&rowsum[row], ov);
        }
    }
    __syncthreads();
    if(tid < BM){
        int t = t0 + tid;
        if(t < T) score[t] = sigf(rowsum[tid]);
    }
}

extern "C" void kernel_launch(void* const* d_in, const int* in_sizes, int n_in,
                              void* d_out, int out_size, void* d_ws, size_t ws_size,
                              hipStream_t stream){
    const float* x    = (const float*)d_in[0];
    const float* remb = (const float*)d_in[1];
    const float* W1   = (const float*)d_in[2];
    const float* b1   = (const float*)d_in[3];
    const float* W2   = (const float*)d_in[4];
    const float* b2   = (const float*)d_in[5];
    const float* Wih  = (const float*)d_in[6];
    const float* b_ih = (const float*)d_in[8];
    const float* b_hh = (const float*)d_in[9];
    const int*   ei   = (const int*)d_in[10];
    const int*   trip = (const int*)d_in[11];
    float* score = (float*)d_out;

    const int N = in_sizes[0]/NF;       // 15000
    const int E = in_sizes[10]/2;       // 200000
    const int T = in_sizes[11]/3;       // 100000
    const int* src = ei;
    const int* dst = ei + E;

    float* ws = (float*)d_ws;
    size_t o = 0;
    ushort* img  = (ushort*)(ws+o); o += (size_t)12*64*64*8/2;   // 786 KB
    float* zbf   = ws+o;            o += (size_t)N*D2;           // fp32 z, 7.7 MB
    int*   cnt    = (int*)(ws+o);   o += (size_t)((N+8)&~7);
    int*   rowptr = (int*)(ws+o);   o += (size_t)((N+8)&~7);
    int*   rowcur = (int*)(ws+o);   o += (size_t)((N+8)&~7);
    int*   esrc   = (int*)(ws+o);   o += (size_t)E;
    float* enorm  = ws+o;           o += (size_t)E;
    float* dinv   = ws+o;           o += (size_t)((N+7)&~7);
    float* h1     = ws+o;           o += (size_t)N*D1;
    float* hbuf   = ws+o;           o += (size_t)N*D1;
    float* hz     = ws+o;           o += (size_t)N*D2;
    (void)ws_size; (void)n_in; (void)out_size;

    hipMemsetAsync(cnt, 0, (size_t)N*sizeof(int), stream);

    k_wimgB<<<dim3((12*64*64+255)/256), dim3(256), 0, stream>>>(Wih, img);
    k_deg  <<<dim3((E+255)/256), dim3(256), 0, stream>>>(dst, cnt, E);
    k_scan <<<dim3(1), dim3(256), 0, stream>>>(cnt, rowptr, rowcur, dinv, N, E);
    k_fill <<<dim3((E+255)/256), dim3(256), 0, stream>>>(src, dst, dinv, rowcur, esrc, enorm, E);
    k_h1   <<<dim3((N+3)/4), dim3(256), 0, stream>>>(x, W1, h1, N);
    k_gath1<<<dim3((N+3)/4), dim3(256), 0, stream>>>(h1, rowptr, esrc, enorm, dinv, b1, hbuf, N);
    k_hz   <<<dim3(N), dim3(128), 0, stream>>>(hbuf, W2, hz, N);
    k_gath2<<<dim3(N), dim3(128), 0, stream>>>(hz, rowptr, esrc, enorm, dinv, b2, zbf, N);
    k_big  <<<dim3((T+BM-1)/BM), dim3(256), 0, stream>>>(remb, img, zbf, b_ih, b_hh, trip, score, T);
}